// Round 2
// baseline (166.919 us; speedup 1.0000x reference)
//
#include <hip/hip_runtime.h>

#define T_LEN   65536
#define CHUNK   64
#define NTHREADS 1024   // T_LEN / CHUNK

__launch_bounds__(NTHREADS, 4)
__global__ void iir_scan_kernel(const float* __restrict__ x,
                                const float* __restrict__ b,
                                const float* __restrict__ a,
                                float* __restrict__ y)
{
    const int row = blockIdx.x;
    const int tid = threadIdx.x;
    const long base = (long)row * T_LEN + (long)tid * CHUNK;

    const float inv_a0 = 1.0f / a[0];
    const float b0 = b[0] * inv_a0, b1 = b[1] * inv_a0, b2 = b[2] * inv_a0;
    const float c1 = a[1] * inv_a0, c2 = a[2] * inv_a0;

    // FIR boundary values (x[-1], x[-2] relative to this chunk; zero at row start)
    float xm1 = 0.f, xm2 = 0.f;
    if (tid > 0) {
        xm1 = x[base - 1];
        xm2 = x[base - 2];
    }

    // ---- load x chunk (float4) and compute u = FIR(x) into registers ----
    float u[CHUNK];
    const float4* xv = (const float4*)(x + base);
    #pragma unroll
    for (int q = 0; q < CHUNK / 4; ++q) {
        float4 v = xv[q];
        u[4*q+0] = b0*v.x + b1*xm1 + b2*xm2;
        u[4*q+1] = b0*v.y + b1*v.x + b2*xm1;
        u[4*q+2] = b0*v.z + b1*v.y + b2*v.x;
        u[4*q+3] = b0*v.w + b1*v.z + b2*v.y;
        xm2 = v.z; xm1 = v.w;
    }

    // ---- pass 1: zero-init recurrence, keep end state (v_i) ----
    float yp1 = 0.f, yp2 = 0.f;
    #pragma unroll
    for (int j = 0; j < CHUNK; ++j) {
        float yj = u[j] - c1 * yp1 - c2 * yp2;
        yp2 = yp1; yp1 = yj;
    }
    float s0 = yp1, s1 = yp2;   // (y_hat[63], y_hat[62])

    // ---- P = A^CHUNK by squaring, A = [[-c1,-c2],[1,0]] ----
    float m00 = -c1, m01 = -c2, m10 = 1.f, m11 = 0.f;
    #pragma unroll
    for (int k = 0; k < 6; ++k) {   // 2^6 = 64 = CHUNK
        float n00 = m00*m00 + m01*m10;
        float n01 = m00*m01 + m01*m11;
        float n10 = m10*m00 + m11*m10;
        float n11 = m10*m01 + m11*m11;
        m00 = n00; m01 = n01; m10 = n10; m11 = n11;
    }

    // ---- Hillis-Steele inclusive linear scan over the block ----
    // Invariant after step k: thread i holds sum_{j=max(0,i-2^k+1)}^{i} A^{64(i-j)} v_j
    __shared__ float2 sbuf[2][NTHREADS];
    int cur = 0;
    sbuf[cur][tid] = make_float2(s0, s1);
    __syncthreads();
    #pragma unroll
    for (int k = 0; k < 10; ++k) {  // 2^10 = 1024 = NTHREADS
        int off = 1 << k;
        float2 prev = (tid >= off) ? sbuf[cur][tid - off] : make_float2(0.f, 0.f);
        s0 = s0 + m00 * prev.x + m01 * prev.y;
        s1 = s1 + m10 * prev.x + m11 * prev.y;
        sbuf[cur ^ 1][tid] = make_float2(s0, s1);
        __syncthreads();
        cur ^= 1;
        // M <- M^2  (now A^(64*2^(k+1)))
        float n00 = m00*m00 + m01*m10;
        float n01 = m00*m01 + m01*m11;
        float n10 = m10*m00 + m11*m10;
        float n11 = m10*m01 + m11*m11;
        m00 = n00; m01 = n01; m10 = n10; m11 = n11;
    }
    // exclusive result: incoming state for this chunk = S_{tid-1}
    float2 sin_ = (tid > 0) ? sbuf[cur][tid - 1] : make_float2(0.f, 0.f);

    // ---- pass 2: rerun recurrence with correct seed, write y ----
    yp1 = sin_.x; yp2 = sin_.y;
    float4* yv = (float4*)(y + base);
    #pragma unroll
    for (int q = 0; q < CHUNK / 4; ++q) {
        float4 o;
        o.x = u[4*q+0] - c1 * yp1 - c2 * yp2;
        o.y = u[4*q+1] - c1 * o.x - c2 * yp1;
        o.z = u[4*q+2] - c1 * o.y - c2 * o.x;
        o.w = u[4*q+3] - c1 * o.z - c2 * o.y;
        yp2 = o.z; yp1 = o.w;
        yv[q] = o;
    }
}

extern "C" void kernel_launch(void* const* d_in, const int* in_sizes, int n_in,
                              void* d_out, int out_size, void* d_ws, size_t ws_size,
                              hipStream_t stream) {
    const float* x = (const float*)d_in[0];
    const float* b = (const float*)d_in[1];
    const float* a = (const float*)d_in[2];
    float* y = (float*)d_out;

    const int B = in_sizes[0] / T_LEN;   // 512 rows
    iir_scan_kernel<<<B, NTHREADS, 0, stream>>>(x, b, a, y);
}

// Round 3
// 156.131 us; speedup vs baseline: 1.0691x; 1.0691x over previous
//
#include <hip/hip_runtime.h>

#define T_LEN   65536
#define CHUNK   64
#define NT      1024   // threads per block = T_LEN / CHUNK
#define NW      16     // waves per block

__launch_bounds__(NT, 4)
__global__ void iir_scan_kernel(const float* __restrict__ x,
                                const float* __restrict__ bco,
                                const float* __restrict__ aco,
                                float* __restrict__ y)
{
    const int row  = blockIdx.x;
    const int tid  = threadIdx.x;
    const int wave = tid >> 6;
    const int lane = tid & 63;
    const long base = (long)row * T_LEN + (long)tid * CHUNK;

    const float inv_a0 = 1.0f / aco[0];
    const float b0 = bco[0] * inv_a0, b1 = bco[1] * inv_a0, b2 = bco[2] * inv_a0;
    const float c1 = aco[1] * inv_a0, c2 = aco[2] * inv_a0;

    // FIR boundary values (x[-1], x[-2] relative to this chunk; zero at row start)
    float xm1 = 0.f, xm2 = 0.f;
    if (tid > 0) {
        xm1 = x[base - 1];
        xm2 = x[base - 2];
    }

    // ---- load x chunk (float4) and compute u = FIR(x) into registers ----
    float u[CHUNK];
    const float4* xv = (const float4*)(x + base);
    #pragma unroll
    for (int q = 0; q < CHUNK / 4; ++q) {
        float4 v = xv[q];
        u[4*q+0] = b0*v.x + b1*xm1 + b2*xm2;
        u[4*q+1] = b0*v.y + b1*v.x + b2*xm1;
        u[4*q+2] = b0*v.z + b1*v.y + b2*v.x;
        u[4*q+3] = b0*v.w + b1*v.z + b2*v.y;
        xm2 = v.z; xm1 = v.w;
    }

    // Launder u[] so the compiler cannot rematerialize it from global x
    // (that re-load was ~100 MB of extra FETCH in the previous version).
    #pragma unroll
    for (int j = 0; j < CHUNK; ++j) asm volatile("" : "+v"(u[j]));

    // ---- pass 1: zero-init recurrence, keep end state (v_i) ----
    float yp1 = 0.f, yp2 = 0.f;
    #pragma unroll
    for (int j = 0; j < CHUNK; ++j) {
        float yj = u[j] - c1 * yp1 - c2 * yp2;
        yp2 = yp1; yp1 = yj;
    }
    float s0 = yp1, s1 = yp2;   // (y_hat[63], y_hat[62])

    // ---- P = A^CHUNK by squaring, A = [[-c1,-c2],[1,0]] ----
    float m00 = -c1, m01 = -c2, m10 = 1.f, m11 = 0.f;
    #pragma unroll
    for (int k = 0; k < 6; ++k) {   // 2^6 = 64 = CHUNK
        float n00 = m00*m00 + m01*m10;
        float n01 = m00*m01 + m01*m11;
        float n10 = m10*m00 + m11*m10;
        float n11 = m10*m01 + m11*m11;
        m00 = n00; m01 = n01; m10 = n10; m11 = n11;
    }

    // ---- Hillis-Steele inclusive linear scan over the block ----
    __shared__ float2 sbuf[2][NT];
    int cur = 0;
    sbuf[cur][tid] = make_float2(s0, s1);
    __syncthreads();
    #pragma unroll
    for (int k = 0; k < 10; ++k) {  // 2^10 = 1024 = NT
        int off = 1 << k;
        float2 prev = (tid >= off) ? sbuf[cur][tid - off] : make_float2(0.f, 0.f);
        s0 = s0 + m00 * prev.x + m01 * prev.y;
        s1 = s1 + m10 * prev.x + m11 * prev.y;
        sbuf[cur ^ 1][tid] = make_float2(s0, s1);
        __syncthreads();
        cur ^= 1;
        // M <- M^2  (now A^(64*2^(k+1)))
        float n00 = m00*m00 + m01*m10;
        float n01 = m00*m01 + m01*m11;
        float n10 = m10*m00 + m11*m10;
        float n11 = m10*m01 + m11*m11;
        m00 = n00; m01 = n01; m10 = n10; m11 = n11;
    }
    // exclusive result: incoming state for this chunk = S_{tid-1}
    float2 sin_ = (tid > 0) ? sbuf[cur][tid - 1] : make_float2(0.f, 0.f);

    // ---- pass 2: rerun recurrence with correct seed; y overwrites u[] ----
    yp1 = sin_.x; yp2 = sin_.y;
    #pragma unroll
    for (int j = 0; j < CHUNK; ++j) {
        float yj = u[j] - c1 * yp1 - c2 * yp2;
        yp2 = yp1; yp1 = yj;
        u[j] = yj;
    }

    // ---- coalesced store via per-wave LDS transpose (no block syncs) ----
    // Wave w owns row span [w*4096, (w+1)*4096). Sub-phase q: lanes
    // 16q..16q+15 dump their full chunks into a padded [16][65] buffer
    // (conflict-free), then all 64 lanes emit contiguous float4 stores.
    __shared__ float tbuf[NW][16][65];
    float* wb = &tbuf[wave][0][0];
    const long span = (long)row * T_LEN + (long)wave * (CHUNK * 64);

    #pragma unroll
    for (int q = 0; q < 4; ++q) {
        if ((lane >> 4) == q) {
            const int l = lane & 15;
            #pragma unroll
            for (int j = 0; j < CHUNK; ++j)
                wb[l * 65 + j] = u[j];
        }
        __builtin_amdgcn_wave_barrier();
        #pragma unroll
        for (int r = 0; r < 4; ++r) {
            const int crow = 4 * r + (lane >> 4);
            const int ccol = 4 * (lane & 15);
            float4 o;
            o.x = wb[crow * 65 + ccol + 0];
            o.y = wb[crow * 65 + ccol + 1];
            o.z = wb[crow * 65 + ccol + 2];
            o.w = wb[crow * 65 + ccol + 3];
            *(float4*)(y + span + q * 1024 + r * 256 + 4 * lane) = o;
        }
        __builtin_amdgcn_wave_barrier();
    }
}

extern "C" void kernel_launch(void* const* d_in, const int* in_sizes, int n_in,
                              void* d_out, int out_size, void* d_ws, size_t ws_size,
                              hipStream_t stream) {
    const float* x = (const float*)d_in[0];
    const float* b = (const float*)d_in[1];
    const float* a = (const float*)d_in[2];
    float* y = (float*)d_out;

    const int B = in_sizes[0] / T_LEN;   // 512 rows
    iir_scan_kernel<<<B, NT, 0, stream>>>(x, b, a, y);
}

// Round 4
// 69.627 us; speedup vs baseline: 2.3973x; 2.2424x over previous
//
#include <hip/hip_runtime.h>

#define T_LEN 65536
#define HALF  32768
#define CHUNK 32          // per-thread elements per phase (u[32] fits registers)
#define NT    1024        // threads per block
#define NW    16          // waves per block

__attribute__((amdgpu_flat_work_group_size(NT, NT), amdgpu_waves_per_eu(4, 4)))
__global__ void iir_scan_kernel(const float* __restrict__ x,
                                const float* __restrict__ bco,
                                const float* __restrict__ aco,
                                float* __restrict__ y)
{
    const int row  = blockIdx.x;
    const int tid  = threadIdx.x;
    const int wave = tid >> 6;
    const int lane = tid & 63;
    const long rowbase = (long)row * T_LEN;

    const float inv_a0 = 1.0f / aco[0];
    const float b0 = bco[0] * inv_a0, b1 = bco[1] * inv_a0, b2 = bco[2] * inv_a0;
    const float c1 = aco[1] * inv_a0, c2 = aco[2] * inv_a0;

    __shared__ float2 sbuf[2][NT];        // 16 KB scan buffer
    __shared__ float  tbuf[NW][16][36];   // 36 KB per-wave transpose (36 = 32 + pad, 16B-aligned rows)
    __shared__ float2 carry_sm;           // phase 0 -> phase 1 state

    #pragma unroll
    for (int h = 0; h < 2; ++h) {
        float2 carry = make_float2(0.f, 0.f);
        if (h) carry = carry_sm;          // visible: written before end-of-phase __syncthreads

        const long base = rowbase + (long)(h * HALF) + (long)tid * CHUNK;

        // FIR boundary (x[-1], x[-2] rel. to this chunk; zero only at row start)
        float xm1 = 0.f, xm2 = 0.f;
        if (h > 0 || tid > 0) { xm1 = x[base - 1]; xm2 = x[base - 2]; }

        // ---- fused: load x, FIR -> u[32] (kept in regs), zero-state recurrence ----
        float u[CHUNK];
        float yp1 = 0.f, yp2 = 0.f;
        const float4* xv = (const float4*)(x + base);
        #pragma unroll
        for (int q = 0; q < CHUNK / 4; ++q) {
            float4 v = xv[q];
            u[4*q+0] = b0*v.x + b1*xm1 + b2*xm2;
            u[4*q+1] = b0*v.y + b1*v.x + b2*xm1;
            u[4*q+2] = b0*v.z + b1*v.y + b2*v.x;
            u[4*q+3] = b0*v.w + b1*v.z + b2*v.y;
            xm2 = v.z; xm1 = v.w;
            float y0 = u[4*q+0] - c1*yp1 - c2*yp2;
            float y1 = u[4*q+1] - c1*y0  - c2*yp1;
            float y2 = u[4*q+2] - c1*y1  - c2*y0;
            float y3 = u[4*q+3] - c1*y2  - c2*y1;
            yp2 = y2; yp1 = y3;
        }
        // keep u[] in VGPRs (no remat from x); 32+working ~55 regs, fits budget
        #pragma unroll
        for (int j = 0; j < CHUNK; ++j) asm volatile("" : "+v"(u[j]));

        float s0 = yp1, s1 = yp2;         // zero-state chunk-end state

        // ---- M = A^CHUNK, A = [[-c1,-c2],[1,0]] ----
        float m00 = -c1, m01 = -c2, m10 = 1.f, m11 = 0.f;
        #pragma unroll
        for (int k = 0; k < 5; ++k) {     // 2^5 = 32 = CHUNK
            float n00 = m00*m00 + m01*m10, n01 = m00*m01 + m01*m11;
            float n10 = m10*m00 + m11*m10, n11 = m10*m01 + m11*m11;
            m00 = n00; m01 = n01; m10 = n10; m11 = n11;
        }

        // carry propagation term: w ends as A^(CHUNK*tid) * carry (folded into squaring chain)
        float wx = carry.x, wy = carry.y;

        // ---- Hillis-Steele linear scan over 1024 chunks ----
        int cur = 0;
        sbuf[cur][tid] = make_float2(s0, s1);
        __syncthreads();
        #pragma unroll
        for (int k = 0; k < 10; ++k) {
            int off = 1 << k;
            float2 prev = (tid >= off) ? sbuf[cur][tid - off] : make_float2(0.f, 0.f);
            s0 = s0 + m00*prev.x + m01*prev.y;
            s1 = s1 + m10*prev.x + m11*prev.y;
            if (tid & off) {              // fold bit k of tid into w
                float nwx = m00*wx + m01*wy;
                float nwy = m10*wx + m11*wy;
                wx = nwx; wy = nwy;
            }
            sbuf[cur ^ 1][tid] = make_float2(s0, s1);
            __syncthreads();
            cur ^= 1;
            float n00 = m00*m00 + m01*m10, n01 = m00*m01 + m01*m11;
            float n10 = m10*m00 + m11*m10, n11 = m10*m01 + m11*m11;
            m00 = n00; m01 = n01; m10 = n10; m11 = n11;
        }
        float2 sin_ = (tid > 0) ? sbuf[cur][tid - 1] : make_float2(0.f, 0.f);

        // ---- pass 2: true seed = exclusive scan + A^(32*tid)*carry ----
        yp1 = sin_.x + wx;
        yp2 = sin_.y + wy;
        #pragma unroll
        for (int j = 0; j < CHUNK; ++j) {
            float yj = u[j] - c1*yp1 - c2*yp2;
            yp2 = yp1; yp1 = yj;
            u[j] = yj;
        }
        if (tid == NT - 1) carry_sm = make_float2(yp1, yp2);  // exact y[end], y[end-1]

        // ---- coalesced store via per-wave LDS transpose ----
        // Wave covers 64 chunks * 32 = 2048 contiguous floats. Sub-phase q:
        // lanes 16q..16q+15 dump chunks into [16][36] rows (float4 writes),
        // then 64 lanes store a fully-contiguous 512-float run (full lines).
        float* wb = &tbuf[wave][0][0];
        const long span = rowbase + (long)(h * HALF) + (long)wave * (CHUNK * 64);
        #pragma unroll
        for (int q = 0; q < 4; ++q) {
            if ((lane >> 4) == q) {
                const int l = lane & 15;
                #pragma unroll
                for (int jj = 0; jj < CHUNK / 4; ++jj)
                    *(float4*)(wb + l*36 + 4*jj) =
                        make_float4(u[4*jj], u[4*jj+1], u[4*jj+2], u[4*jj+3]);
            }
            __builtin_amdgcn_wave_barrier();
            #pragma unroll
            for (int r = 0; r < 2; ++r) {
                int idx = r * 256 + 4 * lane;        // 0..508, step 4
                int cc  = idx >> 5;                  // local chunk 0..15
                int jj  = idx & 31;                  // element 0..28
                float4 o = *(const float4*)(wb + cc*36 + jj);
                *(float4*)(y + span + (long)q*512 + idx) = o;
            }
            __builtin_amdgcn_wave_barrier();
        }
        __syncthreads();   // tbuf/sbuf/carry_sm safe for next phase
    }
}

extern "C" void kernel_launch(void* const* d_in, const int* in_sizes, int n_in,
                              void* d_out, int out_size, void* d_ws, size_t ws_size,
                              hipStream_t stream) {
    const float* x = (const float*)d_in[0];
    const float* b = (const float*)d_in[1];
    const float* a = (const float*)d_in[2];
    float* y = (float*)d_out;

    const int B = in_sizes[0] / T_LEN;   // 512 rows
    iir_scan_kernel<<<B, NT, 0, stream>>>(x, b, a, y);
}

// Round 5
// 63.704 us; speedup vs baseline: 2.6202x; 1.0930x over previous
//
#include <hip/hip_runtime.h>

#define T_LEN 65536
#define HALF  32768
#define CHUNK 32          // per-thread elements per phase
#define NT    1024        // threads per block
#define NW    16          // waves per block
#define TP    40          // tbuf row stride (16B-aligned, spreads start banks)

__attribute__((amdgpu_flat_work_group_size(NT, NT)))
__global__ void iir_scan_kernel(const float* __restrict__ x,
                                const float* __restrict__ bco,
                                const float* __restrict__ aco,
                                float* __restrict__ y)
{
    const int tid  = threadIdx.x;
    const int wave = tid >> 6;
    const int lane = tid & 63;
    const long rowbase = (long)blockIdx.x * T_LEN;

    const float inv_a0 = 1.0f / aco[0];
    const float b0 = bco[0]*inv_a0, b1 = bco[1]*inv_a0, b2 = bco[2]*inv_a0;
    const float c1 = aco[1]*inv_a0, c2 = aco[2]*inv_a0;

    __shared__ float  tbuf[NW][16][TP];   // ~40 KB per-wave transpose
    __shared__ float2 pbuf[NW];           // wave partial states
    __shared__ float2 carry_sm;           // phase 0 -> phase 1 state

    #pragma unroll
    for (int h = 0; h < 2; ++h) {
        float2 carry = make_float2(0.f, 0.f);
        if (h) carry = carry_sm;          // guarded by end-of-phase __syncthreads

        const long base = rowbase + (long)(h * HALF) + (long)tid * CHUNK;

        // FIR boundary (zero only at row start)
        float xm1 = 0.f, xm2 = 0.f;
        if (h > 0 || tid > 0) { xm1 = x[base - 1]; xm2 = x[base - 2]; }

        // ---- fused: load x, FIR -> u[32] (regs), zero-state recurrence ----
        float u[CHUNK];
        float yp1 = 0.f, yp2 = 0.f;
        const float4* xv = (const float4*)(x + base);
        #pragma unroll
        for (int q = 0; q < CHUNK / 4; ++q) {
            float4 v = xv[q];
            u[4*q+0] = b0*v.x + b1*xm1 + b2*xm2;
            u[4*q+1] = b0*v.y + b1*v.x + b2*xm1;
            u[4*q+2] = b0*v.z + b1*v.y + b2*v.x;
            u[4*q+3] = b0*v.w + b1*v.z + b2*v.y;
            xm2 = v.z; xm1 = v.w;
            float y0 = u[4*q+0] - c1*yp1 - c2*yp2;
            float y1 = u[4*q+1] - c1*y0  - c2*yp1;
            float y2 = u[4*q+2] - c1*y1  - c2*y0;
            float y3 = u[4*q+3] - c1*y2  - c2*y1;
            yp2 = y2; yp1 = y3;
        }
        #pragma unroll
        for (int j = 0; j < CHUNK; ++j) asm volatile("" : "+v"(u[j]));  // no remat

        // ---- intra-wave inclusive linear scan via shuffles (no barriers) ----
        // m starts at A^32; after 6 combine+square steps m = A^2048 = D.
        float s0 = yp1, s1 = yp2;
        float m00 = -c1, m01 = -c2, m10 = 1.f, m11 = 0.f;
        #pragma unroll
        for (int k = 0; k < 5; ++k) {     // A -> A^32
            float n00=m00*m00+m01*m10, n01=m00*m01+m01*m11;
            float n10=m10*m00+m11*m10, n11=m10*m01+m11*m11;
            m00=n00; m01=n01; m10=n10; m11=n11;
        }
        #pragma unroll
        for (int k = 0; k < 6; ++k) {
            int off = 1 << k;
            float p0 = __shfl_up(s0, off, 64);
            float p1 = __shfl_up(s1, off, 64);
            if (lane < off) { p0 = 0.f; p1 = 0.f; }
            s0 += m00*p0 + m01*p1;
            s1 += m10*p0 + m11*p1;
            float n00=m00*m00+m01*m10, n01=m00*m01+m01*m11;
            float n10=m10*m00+m11*m10, n11=m10*m01+m11*m11;
            m00=n00; m01=n01; m10=n10; m11=n11;
        }

        // ---- cross-wave: one LDS hop + Horner over <=15 partials ----
        if (lane == 63) pbuf[wave] = make_float2(s0, s1);
        __syncthreads();

        // T_w = D^wave * carry + sum_{j<wave} D^(wave-1-j) P_j   (D = current m)
        float t0 = carry.x, t1 = carry.y;
        for (int j = 0; j < wave; ++j) {   // trip count uniform within wave
            float2 P = pbuf[j];
            float q0 = m00*t0 + m01*t1 + P.x;
            float q1 = m10*t0 + m11*t1 + P.y;
            t0 = q0; t1 = q1;
        }

        // t = A^(32*lane) * T  via binary expansion (rebuild chain from A^32)
        {
            float e00 = -c1, e01 = -c2, e10 = 1.f, e11 = 0.f;
            #pragma unroll
            for (int k = 0; k < 5; ++k) {
                float n00=e00*e00+e01*e10, n01=e00*e01+e01*e11;
                float n10=e10*e00+e11*e10, n11=e10*e01+e11*e11;
                e00=n00; e01=n01; e10=n10; e11=n11;
            }
            #pragma unroll
            for (int k = 0; k < 6; ++k) {
                if (lane & (1 << k)) {
                    float q0 = e00*t0 + e01*t1;
                    float q1 = e10*t0 + e11*t1;
                    t0 = q0; t1 = q1;
                }
                float n00=e00*e00+e01*e10, n01=e00*e01+e01*e11;
                float n10=e10*e00+e11*e10, n11=e10*e01+e11*e11;
                e00=n00; e01=n01; e10=n10; e11=n11;
            }
        }

        // exclusive within-wave part
        float e0 = __shfl_up(s0, 1, 64);
        float e1 = __shfl_up(s1, 1, 64);
        if (lane == 0) { e0 = 0.f; e1 = 0.f; }

        // ---- pass 2: true seed, y overwrites u[] ----
        yp1 = e0 + t0;
        yp2 = e1 + t1;
        #pragma unroll
        for (int j = 0; j < CHUNK; ++j) {
            float yj = u[j] - c1*yp1 - c2*yp2;
            yp2 = yp1; yp1 = yj;
            u[j] = yj;
        }
        if (tid == NT - 1) carry_sm = make_float2(yp1, yp2);

        // ---- coalesced store via per-wave LDS transpose (wave barriers only) ----
        float* wb = &tbuf[wave][0][0];
        const long span = rowbase + (long)(h * HALF) + (long)wave * (CHUNK * 64);
        #pragma unroll
        for (int q = 0; q < 4; ++q) {
            if ((lane >> 4) == q) {
                const int l = lane & 15;
                #pragma unroll
                for (int jj = 0; jj < CHUNK / 4; ++jj)
                    *(float4*)(wb + l*TP + 4*jj) =
                        make_float4(u[4*jj], u[4*jj+1], u[4*jj+2], u[4*jj+3]);
            }
            __builtin_amdgcn_wave_barrier();
            #pragma unroll
            for (int r = 0; r < 2; ++r) {
                int idx = r * 256 + 4 * lane;   // contiguous 512-float run
                int cc  = idx >> 5;
                int jj  = idx & 31;
                float4 o = *(const float4*)(wb + cc*TP + jj);
                *(float4*)(y + span + (long)q*512 + idx) = o;
            }
            __builtin_amdgcn_wave_barrier();
        }
        __syncthreads();   // pbuf/tbuf/carry_sm safe for next phase
    }
}

extern "C" void kernel_launch(void* const* d_in, const int* in_sizes, int n_in,
                              void* d_out, int out_size, void* d_ws, size_t ws_size,
                              hipStream_t stream) {
    const float* x = (const float*)d_in[0];
    const float* b = (const float*)d_in[1];
    const float* a = (const float*)d_in[2];
    float* y = (float*)d_out;

    const int B = in_sizes[0] / T_LEN;   // 512 rows
    iir_scan_kernel<<<B, NT, 0, stream>>>(x, b, a, y);
}

// Round 7
// 60.325 us; speedup vs baseline: 2.7670x; 1.0560x over previous
//
#include <hip/hip_runtime.h>

#define T_LEN 65536
#define HALF  32768
#define CHUNK 32          // per-thread elements per phase
#define NT    1024        // threads per block
#define NW    16          // waves per block
#define TP    36          // tbuf row stride: start banks 4*l mod 32 -> 2-way (free)

typedef float vfloat4 __attribute__((ext_vector_type(4)));  // clang vector: ok for nontemporal builtin

__attribute__((amdgpu_flat_work_group_size(NT, NT)))
__global__ void iir_scan_kernel(const float* __restrict__ x,
                                const float* __restrict__ bco,
                                const float* __restrict__ aco,
                                float* __restrict__ y)
{
    const int tid  = threadIdx.x;
    const int wave = tid >> 6;
    const int lane = tid & 63;
    const long rowbase = (long)blockIdx.x * T_LEN;

    const float inv_a0 = 1.0f / aco[0];
    const float b0 = bco[0]*inv_a0, b1 = bco[1]*inv_a0, b2 = bco[2]*inv_a0;
    const float c1 = aco[1]*inv_a0, c2 = aco[2]*inv_a0;

    __shared__ float  tbuf[NW][16][TP];   // ~36 KB per-wave transpose
    __shared__ float2 pbuf[NW];           // wave partial states
    __shared__ float2 carry_sm;           // phase 0 -> phase 1 state

    #pragma unroll
    for (int h = 0; h < 2; ++h) {
        float2 carry = make_float2(0.f, 0.f);
        if (h) carry = carry_sm;          // guarded by end-of-phase __syncthreads

        const long base = rowbase + (long)(h * HALF) + (long)tid * CHUNK;

        // FIR boundary (zero only at row start)
        float xm1 = 0.f, xm2 = 0.f;
        if (h > 0 || tid > 0) { xm1 = x[base - 1]; xm2 = x[base - 2]; }

        // ---- fused: load x, FIR -> u[32] (regs), zero-state recurrence ----
        float u[CHUNK];
        float yp1 = 0.f, yp2 = 0.f;
        const float4* xv = (const float4*)(x + base);
        #pragma unroll
        for (int q = 0; q < CHUNK / 4; ++q) {
            float4 v = xv[q];
            u[4*q+0] = b0*v.x + b1*xm1 + b2*xm2;
            u[4*q+1] = b0*v.y + b1*v.x + b2*xm1;
            u[4*q+2] = b0*v.z + b1*v.y + b2*v.x;
            u[4*q+3] = b0*v.w + b1*v.z + b2*v.y;
            xm2 = v.z; xm1 = v.w;
            float y0 = u[4*q+0] - c1*yp1 - c2*yp2;
            float y1 = u[4*q+1] - c1*y0  - c2*yp1;
            float y2 = u[4*q+2] - c1*y1  - c2*y0;
            float y3 = u[4*q+3] - c1*y2  - c2*y1;
            yp2 = y2; yp1 = y3;
        }
        #pragma unroll
        for (int j = 0; j < CHUNK; ++j) asm volatile("" : "+v"(u[j]));  // no remat

        // ---- intra-wave inclusive linear scan via shuffles (no barriers) ----
        float s0 = yp1, s1 = yp2;
        float m00 = -c1, m01 = -c2, m10 = 1.f, m11 = 0.f;
        #pragma unroll
        for (int k = 0; k < 5; ++k) {     // A -> A^32
            float n00=m00*m00+m01*m10, n01=m00*m01+m01*m11;
            float n10=m10*m00+m11*m10, n11=m10*m01+m11*m11;
            m00=n00; m01=n01; m10=n10; m11=n11;
        }
        #pragma unroll
        for (int k = 0; k < 6; ++k) {
            int off = 1 << k;
            float p0 = __shfl_up(s0, off, 64);
            float p1 = __shfl_up(s1, off, 64);
            if (lane < off) { p0 = 0.f; p1 = 0.f; }
            s0 += m00*p0 + m01*p1;
            s1 += m10*p0 + m11*p1;
            float n00=m00*m00+m01*m10, n01=m00*m01+m01*m11;
            float n10=m10*m00+m11*m10, n11=m10*m01+m11*m11;
            m00=n00; m01=n01; m10=n10; m11=n11;
        }

        // ---- cross-wave: one LDS hop + Horner over <=15 partials ----
        if (lane == 63) pbuf[wave] = make_float2(s0, s1);
        __syncthreads();

        // T_w = D^wave * carry + sum_{j<wave} D^(wave-1-j) P_j   (D = m = A^2048)
        float t0 = carry.x, t1 = carry.y;
        for (int j = 0; j < wave; ++j) {
            float2 P = pbuf[j];
            float q0 = m00*t0 + m01*t1 + P.x;
            float q1 = m10*t0 + m11*t1 + P.y;
            t0 = q0; t1 = q1;
        }

        // t = A^(32*lane) * T via binary expansion (rebuild chain from A^32)
        {
            float e00 = -c1, e01 = -c2, e10 = 1.f, e11 = 0.f;
            #pragma unroll
            for (int k = 0; k < 5; ++k) {
                float n00=e00*e00+e01*e10, n01=e00*e01+e01*e11;
                float n10=e10*e00+e11*e10, n11=e10*e01+e11*e11;
                e00=n00; e01=n01; e10=n10; e11=n11;
            }
            #pragma unroll
            for (int k = 0; k < 6; ++k) {
                if (lane & (1 << k)) {
                    float q0 = e00*t0 + e01*t1;
                    float q1 = e10*t0 + e11*t1;
                    t0 = q0; t1 = q1;
                }
                float n00=e00*e00+e01*e10, n01=e00*e01+e01*e11;
                float n10=e10*e00+e11*e10, n11=e10*e01+e11*e11;
                e00=n00; e01=n01; e10=n10; e11=n11;
            }
        }

        // exclusive within-wave part
        float e0 = __shfl_up(s0, 1, 64);
        float e1 = __shfl_up(s1, 1, 64);
        if (lane == 0) { e0 = 0.f; e1 = 0.f; }

        // ---- pass 2: true seed, y overwrites u[] ----
        yp1 = e0 + t0;
        yp2 = e1 + t1;
        #pragma unroll
        for (int j = 0; j < CHUNK; ++j) {
            float yj = u[j] - c1*yp1 - c2*yp2;
            yp2 = yp1; yp1 = yj;
            u[j] = yj;
        }
        if (tid == NT - 1) carry_sm = make_float2(yp1, yp2);

        // ---- coalesced NON-TEMPORAL store via per-wave LDS transpose ----
        // y is written once, never re-read: nt stores bypass L2/L3 so the
        // write stream stops evicting x (keeps x fully L3-resident).
        float* wb = &tbuf[wave][0][0];
        const long span = rowbase + (long)(h * HALF) + (long)wave * (CHUNK * 64);
        #pragma unroll
        for (int q = 0; q < 4; ++q) {
            if ((lane >> 4) == q) {
                const int l = lane & 15;
                #pragma unroll
                for (int jj = 0; jj < CHUNK / 4; ++jj)
                    *(float4*)(wb + l*TP + 4*jj) =
                        make_float4(u[4*jj], u[4*jj+1], u[4*jj+2], u[4*jj+3]);
            }
            __builtin_amdgcn_wave_barrier();
            #pragma unroll
            for (int r = 0; r < 2; ++r) {
                int idx = r * 256 + 4 * lane;   // contiguous 512-float run
                int cc  = idx >> 5;
                int jj  = idx & 31;
                vfloat4 o;
                o.x = wb[cc*TP + jj + 0];
                o.y = wb[cc*TP + jj + 1];
                o.z = wb[cc*TP + jj + 2];
                o.w = wb[cc*TP + jj + 3];
                __builtin_nontemporal_store(o, (vfloat4*)(y + span + (long)q*512 + idx));
            }
            __builtin_amdgcn_wave_barrier();
        }
        __syncthreads();   // pbuf/tbuf/carry_sm safe for next phase
    }
}

extern "C" void kernel_launch(void* const* d_in, const int* in_sizes, int n_in,
                              void* d_out, int out_size, void* d_ws, size_t ws_size,
                              hipStream_t stream) {
    const float* x = (const float*)d_in[0];
    const float* b = (const float*)d_in[1];
    const float* a = (const float*)d_in[2];
    float* y = (float*)d_out;

    const int B = in_sizes[0] / T_LEN;   // 512 rows
    iir_scan_kernel<<<B, NT, 0, stream>>>(x, b, a, y);
}

// Round 8
// 49.428 us; speedup vs baseline: 3.3770x; 1.2205x over previous
//
#include <hip/hip_runtime.h>

#define T_LEN 65536
#define CHUNK 16          // per-thread elements per phase
#define NPH   4           // phases per row
#define PHLEN (T_LEN / NPH)   // 16384 elements per phase
#define NT    1024        // threads per block
#define NW    16          // waves per block
#define TP    20          // tbuf row stride: 16 + 4 pad (16B aligned, 2-way banks = free)

typedef float vfloat4 __attribute__((ext_vector_type(4)));

// Block barrier that does NOT drain vmcnt: prefetch loads stay in flight.
// lgkmcnt(0) gives LDS visibility (pbuf/carry_sm); sched_barrier pins order.
#define BARRIER_LGKM() do {                                   \
    asm volatile("s_waitcnt lgkmcnt(0)" ::: "memory");        \
    __builtin_amdgcn_s_barrier();                             \
    __builtin_amdgcn_sched_barrier(0);                        \
} while (0)

#define SQMAT(a00,a01,a10,a11) {                              \
    float n00=a00*a00+a01*a10, n01=a00*a01+a01*a11;           \
    float n10=a10*a00+a11*a10, n11=a10*a01+a11*a11;           \
    a00=n00; a01=n01; a10=n10; a11=n11; }

__attribute__((amdgpu_flat_work_group_size(NT, NT)))
__global__ void iir_scan_kernel(const float* __restrict__ x,
                                const float* __restrict__ bco,
                                const float* __restrict__ aco,
                                float* __restrict__ y)
{
    const int tid  = threadIdx.x;
    const int wave = tid >> 6;
    const int lane = tid & 63;
    const long rowbase = (long)blockIdx.x * T_LEN;

    const float inv_a0 = 1.0f / aco[0];
    const float b0 = bco[0]*inv_a0, b1 = bco[1]*inv_a0, b2 = bco[2]*inv_a0;
    const float c1 = aco[1]*inv_a0, c2 = aco[2]*inv_a0;

    __shared__ float  tbuf[NW][16][TP];   // ~20 KB per-wave transpose
    __shared__ float2 pbuf[NW];
    __shared__ float2 carry_sm;

    float4 bufA[4], bufB[4];
    float xmA1, xmA2, xmB1, xmB2;

    // ---- prologue: issue phase-0 loads ----
    {
        const long b_ = rowbase + (long)tid * CHUNK;
        const float4* xv = (const float4*)(x + b_);
        bufA[0]=xv[0]; bufA[1]=xv[1]; bufA[2]=xv[2]; bufA[3]=xv[3];
        xmA1 = 0.f; xmA2 = 0.f;
        if (tid > 0) { xmA1 = x[b_ - 1]; xmA2 = x[b_ - 2]; }
    }

// One phase: prefetch next x, FIR+pass1, 3-level scan, pass2, transposed nt store.
#define PHASE(CUR, XM1, XM2, NXT, NXM1, NXM2, H, PRE)                          \
  {                                                                            \
    if (PRE) { /* issue next-phase loads FIRST: in flight all phase long */    \
      const long nb_ = rowbase + (long)((H)+1) * PHLEN + (long)tid * CHUNK;    \
      const float4* nxv_ = (const float4*)(x + nb_);                           \
      NXT[0]=nxv_[0]; NXT[1]=nxv_[1]; NXT[2]=nxv_[2]; NXT[3]=nxv_[3];          \
      NXM1 = x[nb_ - 1]; NXM2 = x[nb_ - 2];                                    \
    }                                                                          \
    float2 carry = make_float2(0.f, 0.f);                                      \
    if (H) carry = carry_sm;                                                   \
    /* ---- FIR + zero-state recurrence; u overwrites CUR in place ---- */     \
    float yp1 = 0.f, yp2 = 0.f;                                                \
    {                                                                          \
      float fm1 = XM1, fm2 = XM2;                                              \
      _Pragma("unroll")                                                        \
      for (int q = 0; q < 4; ++q) {                                            \
        float4 v = CUR[q];                                                     \
        float u0 = b0*v.x + b1*fm1 + b2*fm2;                                   \
        float u1 = b0*v.y + b1*v.x + b2*fm1;                                   \
        float u2 = b0*v.z + b1*v.y + b2*v.x;                                   \
        float u3 = b0*v.w + b1*v.z + b2*v.y;                                   \
        fm2 = v.z; fm1 = v.w;                                                  \
        CUR[q] = make_float4(u0,u1,u2,u3);                                     \
        float y0 = u0 - c1*yp1 - c2*yp2;                                       \
        float y1 = u1 - c1*y0  - c2*yp1;                                       \
        float y2 = u2 - c1*y1  - c2*y0;                                        \
        float y3 = u3 - c1*y2  - c2*y1;                                        \
        yp2 = y2; yp1 = y3;                                                    \
      }                                                                        \
    }                                                                          \
    _Pragma("unroll")                                                          \
    for (int q = 0; q < 4; ++q)                                                \
      asm volatile("" : "+v"(CUR[q].x), "+v"(CUR[q].y),                        \
                        "+v"(CUR[q].z), "+v"(CUR[q].w));  /* no remat */       \
    /* ---- intra-wave scan (shuffles); m: A -> A^16 -> A^1024 ---- */         \
    float s0 = yp1, s1 = yp2;                                                  \
    float m00 = -c1, m01 = -c2, m10 = 1.f, m11 = 0.f;                          \
    _Pragma("unroll")                                                          \
    for (int k = 0; k < 4; ++k) SQMAT(m00,m01,m10,m11)                         \
    _Pragma("unroll")                                                          \
    for (int k = 0; k < 6; ++k) {                                              \
      int off = 1 << k;                                                        \
      float p0 = __shfl_up(s0, off, 64);                                       \
      float p1 = __shfl_up(s1, off, 64);                                       \
      if (lane < off) { p0 = 0.f; p1 = 0.f; }                                  \
      s0 += m00*p0 + m01*p1;                                                   \
      s1 += m10*p0 + m11*p1;                                                   \
      SQMAT(m00,m01,m10,m11)                                                   \
    }                                                                          \
    if (lane == 63) pbuf[wave] = make_float2(s0, s1);                          \
    BARRIER_LGKM();                                                            \
    /* ---- cross-wave Horner with D = A^1024 (= m) ---- */                    \
    float t0 = carry.x, t1 = carry.y;                                          \
    for (int j = 0; j < wave; ++j) {                                           \
      float2 P = pbuf[j];                                                      \
      float q0 = m00*t0 + m01*t1 + P.x;                                        \
      float q1 = m10*t0 + m11*t1 + P.y;                                        \
      t0 = q0; t1 = q1;                                                        \
    }                                                                          \
    /* t = A^(16*lane) * T via binary expansion */                             \
    {                                                                          \
      float e00 = -c1, e01 = -c2, e10 = 1.f, e11 = 0.f;                        \
      _Pragma("unroll")                                                        \
      for (int k = 0; k < 4; ++k) SQMAT(e00,e01,e10,e11)                       \
      _Pragma("unroll")                                                        \
      for (int k = 0; k < 6; ++k) {                                            \
        if (lane & (1 << k)) {                                                 \
          float q0 = e00*t0 + e01*t1;                                          \
          float q1 = e10*t0 + e11*t1;                                          \
          t0 = q0; t1 = q1;                                                    \
        }                                                                      \
        SQMAT(e00,e01,e10,e11)                                                 \
      }                                                                        \
    }                                                                          \
    float ex0 = __shfl_up(s0, 1, 64);                                          \
    float ex1 = __shfl_up(s1, 1, 64);                                          \
    if (lane == 0) { ex0 = 0.f; ex1 = 0.f; }                                   \
    /* ---- pass 2: true seed; y overwrites CUR ---- */                        \
    yp1 = ex0 + t0;                                                            \
    yp2 = ex1 + t1;                                                            \
    _Pragma("unroll")                                                          \
    for (int q = 0; q < 4; ++q) {                                              \
      float4 uq = CUR[q];                                                      \
      float y0 = uq.x - c1*yp1 - c2*yp2;                                       \
      float y1 = uq.y - c1*y0  - c2*yp1;                                       \
      float y2 = uq.z - c1*y1  - c2*y0;                                        \
      float y3 = uq.w - c1*y2  - c2*y1;                                        \
      CUR[q] = make_float4(y0,y1,y2,y3);                                       \
      yp2 = y2; yp1 = y3;                                                      \
    }                                                                          \
    if (tid == NT - 1) carry_sm = make_float2(yp1, yp2);                       \
    /* ---- transposed non-temporal store (wave-local) ---- */                 \
    {                                                                          \
      float* wb = &tbuf[wave][0][0];                                           \
      const long span = rowbase + (long)(H) * PHLEN + (long)wave * (CHUNK*64); \
      _Pragma("unroll")                                                        \
      for (int q = 0; q < 4; ++q) {                                            \
        if ((lane >> 4) == q) {                                                \
          const int l = lane & 15;                                             \
          _Pragma("unroll")                                                    \
          for (int jj = 0; jj < 4; ++jj)                                       \
            *(float4*)(wb + l*TP + 4*jj) = CUR[jj];                            \
        }                                                                      \
        __builtin_amdgcn_wave_barrier();                                       \
        {                                                                      \
          int idx = 4 * lane;            /* contiguous 256-float run */        \
          int cc  = idx >> 4;                                                  \
          int jj  = idx & 15;                                                  \
          vfloat4 o;                                                           \
          o.x = wb[cc*TP + jj + 0];                                            \
          o.y = wb[cc*TP + jj + 1];                                            \
          o.z = wb[cc*TP + jj + 2];                                            \
          o.w = wb[cc*TP + jj + 3];                                            \
          __builtin_nontemporal_store(o,                                       \
              (vfloat4*)(y + span + (long)q*256 + idx));                       \
        }                                                                      \
        __builtin_amdgcn_wave_barrier();                                       \
      }                                                                        \
    }                                                                          \
    BARRIER_LGKM();                                                            \
  }

    PHASE(bufA, xmA1, xmA2, bufB, xmB1, xmB2, 0, 1)
    PHASE(bufB, xmB1, xmB2, bufA, xmA1, xmA2, 1, 1)
    PHASE(bufA, xmA1, xmA2, bufB, xmB1, xmB2, 2, 1)
    PHASE(bufB, xmB1, xmB2, bufA, xmA1, xmA2, 3, 0)

#undef PHASE
}

extern "C" void kernel_launch(void* const* d_in, const int* in_sizes, int n_in,
                              void* d_out, int out_size, void* d_ws, size_t ws_size,
                              hipStream_t stream) {
    const float* x = (const float*)d_in[0];
    const float* b = (const float*)d_in[1];
    const float* a = (const float*)d_in[2];
    float* y = (float*)d_out;

    const int B = in_sizes[0] / T_LEN;   // 512 rows
    iir_scan_kernel<<<B, NT, 0, stream>>>(x, b, a, y);
}